// Round 16
// baseline (139.364 us; speedup 1.0000x reference)
//
#include <hip/hip_runtime.h>

typedef unsigned int u32;
typedef unsigned short u16;
typedef int i32x4 __attribute__((ext_vector_type(4)));
typedef int i32x16 __attribute__((ext_vector_type(16)));

// ws layout (bytes):
//   [0..3]      amax (float)
//   [64..1087]  256 partial maxima (float)
//   [2048..]    Wq2: fragment-major i8, 768 KB, XOR-swizzled slots:
//               slab (nt, ks) at nt*24576 + ks*1024 (1 KB = 64 slots x 16 B)
//               fragment (col c, k-half hi) at slot s' = s ^ ((s>>3)&7),
//               s = 2c + hi  ->  64-lane ds_read_b128 is bank-uniform.
#define WQ_OFF 2048

__device__ __forceinline__ void gld16(const void* g, void* l) {
    __builtin_amdgcn_global_load_lds(
        (const __attribute__((address_space(1))) void*)g,
        (__attribute__((address_space(3))) void*)l, 16, 0, 0);
}

// ---------------------------------------------------------------------------
// absmax two-stage tree (no atomics)
// ---------------------------------------------------------------------------
__global__ __launch_bounds__(256) void amax_stage1(const float* __restrict__ W,
                                                   float* __restrict__ part) {
    int t = blockIdx.x * 256 + threadIdx.x;
    float v = 0.0f;
#pragma unroll
    for (int k = 0; k < 12; ++k) v = fmaxf(v, fabsf(W[t + (k << 16)]));
#pragma unroll
    for (int d = 32; d >= 1; d >>= 1) v = fmaxf(v, __shfl_xor(v, d));
    __shared__ float sm[4];
    if ((threadIdx.x & 63) == 0) sm[threadIdx.x >> 6] = v;
    __syncthreads();
    if (threadIdx.x == 0)
        part[blockIdx.x] = fmaxf(fmaxf(sm[0], sm[1]), fmaxf(sm[2], sm[3]));
}

__global__ __launch_bounds__(256) void amax_stage2(const float* __restrict__ part,
                                                   float* __restrict__ amax) {
    float v = part[threadIdx.x];
#pragma unroll
    for (int d = 32; d >= 1; d >>= 1) v = fmaxf(v, __shfl_xor(v, d));
    __shared__ float sm[4];
    if ((threadIdx.x & 63) == 0) sm[threadIdx.x >> 6] = v;
    __syncthreads();
    if (threadIdx.x == 0)
        amax[0] = fmaxf(fmaxf(sm[0], sm[1]), fmaxf(sm[2], sm[3]));
}

// ---------------------------------------------------------------------------
// quantize W_in [1024][768] f32 -> Wq2 (swizzled fragment-major, see above)
// ---------------------------------------------------------------------------
__global__ __launch_bounds__(192) void quant_k(const float* __restrict__ W,
                                               const float* __restrict__ amax,
                                               u32* __restrict__ Wq4) {
    const int n = blockIdx.x, kd = threadIdx.x;     // kd: dword index 0..191
    float s = 127.0f / amax[0];
    float4 v = ((const float4*)(W + n * 768))[kd];
    int a0 = (int)rintf(v.x * s), a1 = (int)rintf(v.y * s);
    int a2 = (int)rintf(v.z * s), a3 = (int)rintf(v.w * s);
    u32 wq = (u32)(a0 & 0xFF) | ((u32)(a1 & 0xFF) << 8) |
             ((u32)(a2 & 0xFF) << 16) | ((u32)(a3 & 0xFF) << 24);
    const int nt = n >> 5, c = n & 31;
    const int ks = kd >> 3, kb4 = kd & 7;
    const int hi = kb4 >> 2, w4 = kb4 & 3;
    const int slot = (c * 2 + hi);
    const int swz  = slot ^ ((slot >> 3) & 7);      // bijective XOR swizzle
    Wq4[nt * 6144 + ks * 256 + swz * 4 + w4] = wq;
}

// ---------------------------------------------------------------------------
// Fused forward — wave-private staging, ZERO-barrier K-loop, counted vmcnt.
// Block = 32 rows, 4 waves; wave w owns n-tiles w*8..w*8+7 (256 cols) for
// all K. Per ks: wave stages its own 8 KB slab-set (8 gld16) into a PRIVATE
// 16 KB double buffer, waits s_waitcnt vmcnt(8) (previous slab landed, next
// still in flight -- never drains to 0), does 1 af-expansion + 8 MFMA
// (expansion shared x8), acc[8] in 128 AGPRs across the whole loop,
// epilogue once at the end. grid 2048 -> 2 blocks/CU (LDS 68 KB);
// waves_per_eu(2,2) pins the 256-reg unified budget (live ~110 V + 128 A).
// ---------------------------------------------------------------------------
__global__ __launch_bounds__(256)
__attribute__((amdgpu_waves_per_eu(2, 2)))
void nnue_fwd(
    const float* __restrict__ x,       // [B][768], values in {0,1}
    const signed char* __restrict__ Wq2,
    const float* __restrict__ amax,
    const float* __restrict__ b_in,    // [1024]
    const float* __restrict__ W_h,     // [8][1024]
    const float* __restrict__ b_h,     // [8]
    const float* __restrict__ W_psqt,  // [768]
    float* __restrict__ out) {         // [B]

    __shared__ __align__(16) signed char bufs[4][2][8192];  // 64 KB private
    __shared__ __align__(16) u16 abits16[32][2][24];        // 3 KB
    __shared__ int   cnts[32];
    __shared__ float pss[32];
    __shared__ float comb[32][4];

    const int t = threadIdx.x;
    const int l = t & 63, w = t >> 6;   // 4 waves
    const int cl = l & 31, hi = l >> 5;
    const size_t row0 = (size_t)blockIdx.x << 5;

    // wave-private stage: 8 slabs (own n-tiles) of ks -> bufs[w][b_]
#define STAGE(b_, ks_)                                                      \
    _Pragma("unroll")                                                       \
    for (int i = 0; i < 8; ++i)                                             \
        gld16(Wq2 + (size_t)((w << 3) + i) * 24576                          \
                  + (size_t)(ks_) * 1024 + (l << 4),                        \
              &bufs[w][b_][i << 10]);

    STAGE(0, 0)                 // slab 0 in flight under the A-phase

    // ---- A phase: 8 threads per row pack x-bits, popcount, psqt ---------
    {
        const int row = t >> 3, q = t & 7;          // q: K-eighth (96 k)
        const float4* xr = (const float4*)(x + (row0 + row) * 768) + q * 24;
        const float4* pw = (const float4*)W_psqt + q * 24;
        u32 csum = 0;
        float ps = 0.0f;
#define PKB(f) ((__float_as_uint(f.x) >> 29)         |                      \
                ((__float_as_uint(f.y) >> 29) << 8)  |                      \
                ((__float_as_uint(f.z) >> 29) << 16) |                      \
                ((__float_as_uint(f.w) >> 29) << 24))
#define DOT4(f, p) ps = fmaf(f.x, p.x, ps); ps = fmaf(f.y, p.y, ps);        \
                   ps = fmaf(f.z, p.z, ps); ps = fmaf(f.w, p.w, ps);
#pragma unroll
        for (int j = 0; j < 3; ++j) {               // 3 ks-groups per thread
#pragma unroll
            for (int hh = 0; hh < 2; ++hh) {
                int fi = j * 8 + hh * 4;
                float4 f0 = xr[fi + 0], f1 = xr[fi + 1];
                float4 f2 = xr[fi + 2], f3 = xr[fi + 3];
                float4 p0 = pw[fi + 0], p1 = pw[fi + 1];
                float4 p2 = pw[fi + 2], p3 = pw[fi + 3];
                u32 d0 = PKB(f0), d1 = PKB(f1), d2 = PKB(f2), d3 = PKB(f3);
                csum += d0 + d1 + d2 + d3;          // byte sums <= 24
                DOT4(f0, p0) DOT4(f1, p1) DOT4(f2, p2) DOT4(f3, p3)
                u32 m16 = ((d0 * 0x01020408u) >> 24)
                        | (((d1 * 0x01020408u) >> 24) << 4)
                        | (((d2 * 0x01020408u) >> 24) << 8)
                        | (((d3 * 0x01020408u) >> 24) << 12);
                abits16[row][hh][q * 3 + j] = (u16)m16;
            }
        }
#undef DOT4
#undef PKB
        int cnt = (csum & 0xFF) + ((csum >> 8) & 0xFF) +
                  ((csum >> 16) & 0xFF) + (csum >> 24);
        cnt += __shfl_xor(cnt, 1); cnt += __shfl_xor(cnt, 2);
        cnt += __shfl_xor(cnt, 4);
        ps  += __shfl_xor(ps, 1);  ps  += __shfl_xor(ps, 2);
        ps  += __shfl_xor(ps, 4);
        if (q == 0) { cnts[row] = cnt; pss[row] = ps; }
    }
    __syncthreads();            // the ONLY pre-loop barrier

    // ---- per-lane setup -------------------------------------------------
    u32 Ab[12];
    {
        const uint4* ap = (const uint4*)&abits16[cl][hi][0];
        uint4 A0 = ap[0], A1 = ap[1], A2 = ap[2];
        Ab[0] = A0.x; Ab[1] = A0.y; Ab[2]  = A0.z; Ab[3]  = A0.w;
        Ab[4] = A1.x; Ab[5] = A1.y; Ab[6]  = A1.z; Ab[7]  = A1.w;
        Ab[8] = A2.x; Ab[9] = A2.y; Ab[10] = A2.z; Ab[11] = A2.w;
    }
    const int slot = (cl << 1) | hi;
    const int swzo = (slot ^ ((slot >> 3) & 7)) << 4;   // swizzled byte off

    i32x16 acc[8];
#pragma unroll
    for (int i = 0; i < 8; ++i) acc[i] = (i32x16){0,0,0,0,0,0,0,0,
                                                  0,0,0,0,0,0,0,0};

    // ---- main K-loop: 24 ks, zero barriers, counted vmcnt ----------------
#pragma unroll
    for (int ks = 0; ks < 24; ++ks) {
        if (ks < 23) STAGE((ks + 1) & 1, ks + 1)
        if (ks < 23) asm volatile("s_waitcnt vmcnt(8)" ::: "memory");
        else         asm volatile("s_waitcnt vmcnt(0)" ::: "memory");

        u32 pair = Ab[ks >> 1];
        asm volatile("" : "+v"(pair));          // keep expansion in-loop
        u32 m = (ks & 1) ? (pair >> 16) : (pair & 0xFFFFu);
        i32x4 af;
        af[0] = (int)(((m         & 0xFu) * 0x00204081u) & 0x01010101u);
        af[1] = (int)((((m >> 4)  & 0xFu) * 0x00204081u) & 0x01010101u);
        af[2] = (int)((((m >> 8)  & 0xFu) * 0x00204081u) & 0x01010101u);
        af[3] = (int)((((m >> 12)       ) * 0x00204081u) & 0x01010101u);

        const signed char* cb = &bufs[w][ks & 1][0] + swzo;
#pragma unroll
        for (int tile = 0; tile < 8; ++tile) {
            i32x4 bf = *(const i32x4*)(cb + (tile << 10));
            acc[tile] = __builtin_amdgcn_mfma_i32_32x32x32_i8(
                            af, bf, acc[tile], 0, 0, 0);
        }
    }
#undef STAGE

    // ---- epilogue (once): scale+bias+clip, bucket-head dot ---------------
    const float sc = amax[0] * (1.0f / 127.0f);
    int whoff[16];
#pragma unroll
    for (int g = 0; g < 16; ++g) {
        int er = (g & 3) + ((g >> 2) << 3) + (hi << 2);
        whoff[g] = ((cnts[er] - 1) >> 2) << 10;     // bucket * 1024
    }
    float rs[16];
#pragma unroll
    for (int g = 0; g < 16; ++g) rs[g] = 0.0f;

#pragma unroll
    for (int tile = 0; tile < 8; ++tile) {
        const int col = (w << 8) + (tile << 5) + cl;
        const float bi = b_in[col];
#pragma unroll
        for (int g = 0; g < 16; ++g) {
            float h = fminf(fmaxf(fmaf((float)acc[tile][g], sc, bi),
                                  0.0f), 1.0f);
            rs[g] = fmaf(h, W_h[whoff[g] + col], rs[g]);
        }
    }

    // reduce over the 32 col-lanes (stays within each hi half)
#pragma unroll
    for (int g = 0; g < 16; ++g) {
#pragma unroll
        for (int d = 1; d < 32; d <<= 1) rs[g] += __shfl_xor(rs[g], d);
    }
    if (cl == 0) {
#pragma unroll
        for (int g = 0; g < 16; ++g) {
            int er = (g & 3) + ((g >> 2) << 3) + (hi << 2);
            comb[er][w] = rs[g];
        }
    }
    __syncthreads();
    if (t < 32) {
        out[row0 + t] = comb[t][0] + comb[t][1] + comb[t][2] + comb[t][3]
                        + pss[t] + b_h[(cnts[t] - 1) >> 2];
    }
}

extern "C" void kernel_launch(void* const* d_in, const int* in_sizes, int n_in,
                              void* d_out, int out_size, void* d_ws, size_t ws_size,
                              hipStream_t stream) {
    const float* x      = (const float*)d_in[0];
    const float* W_in   = (const float*)d_in[1];
    const float* b_in   = (const float*)d_in[2];
    const float* W_h    = (const float*)d_in[3];
    const float* b_h    = (const float*)d_in[4];
    const float* W_psqt = (const float*)d_in[5];
    float* out = (float*)d_out;

    float* amax = (float*)d_ws;
    float* part = (float*)((char*)d_ws + 64);
    signed char* Wq2 = (signed char*)d_ws + WQ_OFF;     // 768 KB

    amax_stage1<<<256, 256, 0, stream>>>(W_in, part);
    amax_stage2<<<1, 256, 0, stream>>>(part, amax);
    quant_k<<<1024, 192, 0, stream>>>(W_in, amax, (u32*)Wq2);

    int B = out_size;                   // 65536
    nnue_fwd<<<B / 32, 256, 0, stream>>>(x, Wq2, amax, b_in, W_h, b_h,
                                         W_psqt, out);
}